// Round 1
// baseline (797.789 us; speedup 1.0000x reference)
//
#include <hip/hip_runtime.h>
#include <hip/hip_bf16.h>
#include <stdint.h>

// ---------- types ----------
using bf16x8 = __attribute__((ext_vector_type(8))) __bf16;
using s16x8  = __attribute__((ext_vector_type(8))) short;
using f32x4  = __attribute__((ext_vector_type(4))) float;

__device__ __forceinline__ uint16_t f2bf(float f) {
    uint32_t u = __builtin_bit_cast(uint32_t, f);
    u += 0x7fffu + ((u >> 16) & 1u);   // RNE
    return (uint16_t)(u >> 16);
}
__device__ __forceinline__ float bf2f(uint16_t h) {
    return __builtin_bit_cast(float, (uint32_t)h << 16);
}

// async global->LDS, 16B per lane. LDS dest must be wave-uniform base (+lane*16 by HW).
__device__ __forceinline__ void async16(uint16_t* lds_dst, const uint16_t* g_src) {
    __builtin_amdgcn_global_load_lds(
        (const __attribute__((address_space(1))) void*)g_src,
        (__attribute__((address_space(3))) void*)lds_dst,
        16, 0, 0);
}

// ---------- K0: transpose + f32->bf16 convert (for weights) ----------
// out[c][r] = bf16(in[r][c]); in is R x C, out is C x R
__global__ void tconv_k(const float* __restrict__ in, uint16_t* __restrict__ out,
                        int R, int C) {
    int idx = blockIdx.x * 256 + threadIdx.x;
    if (idx >= R * C) return;
    int r = idx / C, c = idx - r * C;
    out[(long)c * R + r] = f2bf(in[idx]);
}

// ---------- GEMM: C[M x N] = A[M x K] * Bt[N x K]^T, 128x128 tile, BK=64 ----------
// A: f32 (reg-staged + cvt) or bf16 (global_load_lds). Bt: bf16 row-major [N][K].
// LDS rows are 128B (8 chunks of 16B); XOR swizzle slot = chunk ^ (row&7).
template<bool AF32, bool OUTF32>
__global__ __launch_bounds__(256, 2)
void gemm_k(const void* __restrict__ Ap, const uint16_t* __restrict__ Bt,
            void* __restrict__ Cp, const float* __restrict__ bias,
            int K, int lda, int ldc, int mtiles, int ntiles,
            long abr /*A batch rows*/, long bbe /*B batch elems*/, long cbr /*C batch rows*/)
{
    __shared__ uint16_t Al[128 * 64];
    __shared__ uint16_t Bl[128 * 64];
    const int tid  = threadIdx.x;
    const int lane = tid & 63;
    const int wv   = tid >> 6;
    const int wr   = wv >> 1, wc = wv & 1;

    const int per   = mtiles * ntiles;
    const int batch = blockIdx.x / per;
    const int rem   = blockIdx.x - batch * per;
    const int mt    = rem / ntiles, nt = rem - mt * ntiles;

    const long arow0 = abr * batch + (long)mt * 128;
    const uint16_t* btb = Bt + bbe * batch + (long)nt * 128 * K;

    f32x4 acc[4][4];
#pragma unroll
    for (int m = 0; m < 4; ++m)
#pragma unroll
        for (int n = 0; n < 4; ++n) acc[m][n] = (f32x4){0.f, 0.f, 0.f, 0.f};

    for (int k0 = 0; k0 < K; k0 += 64) {
        // ---- stage B (always bf16, async direct-to-LDS, pre-swizzled source) ----
#pragma unroll
        for (int i = 0; i < 4; ++i) {
            int cb  = i * 256 + wv * 64;      // wave-uniform chunk base
            int ci  = cb + lane;
            int row = ci >> 3;
            int cs  = (ci & 7) ^ (row & 7);   // inverse swizzle on global source
            async16(&Bl[cb * 8], btb + (long)row * K + (k0 + cs * 8));
        }
        // ---- stage A ----
        if constexpr (AF32) {
            const float* Af = (const float*)Ap;
#pragma unroll
            for (int j = 0; j < 4; ++j) {
                int ci  = j * 256 + tid;
                int row = ci >> 3;
                int sl  = ci & 7;
                const float* g = Af + (arow0 + row) * (long)lda + (k0 + sl * 8);
                float4 v0 = *(const float4*)g;
                float4 v1 = *(const float4*)(g + 4);
                uint16_t t[8];
                t[0] = f2bf(v0.x); t[1] = f2bf(v0.y); t[2] = f2bf(v0.z); t[3] = f2bf(v0.w);
                t[4] = f2bf(v1.x); t[5] = f2bf(v1.y); t[6] = f2bf(v1.z); t[7] = f2bf(v1.w);
                // swizzled LDS write
                *(s16x8*)&Al[row * 64 + ((sl ^ (row & 7)) * 8)] = *(const s16x8*)t;
            }
        } else {
            const uint16_t* Ab = (const uint16_t*)Ap;
#pragma unroll
            for (int i = 0; i < 4; ++i) {
                int cb  = i * 256 + wv * 64;
                int ci  = cb + lane;
                int row = ci >> 3;
                int cs  = (ci & 7) ^ (row & 7);
                async16(&Al[cb * 8], Ab + (arow0 + row) * (long)lda + (k0 + cs * 8));
            }
        }
        __syncthreads();   // drains vmcnt+lgkmcnt before barrier (compiler-inserted)

        // ---- compute: 2 k-subs x 4x4 fragments ----
#pragma unroll
        for (int ks = 0; ks < 2; ++ks) {
            bf16x8 af[4], bfrag[4];
#pragma unroll
            for (int m = 0; m < 4; ++m) {
                int row = wr * 64 + m * 16 + (lane & 15);
                int ch  = ks * 4 + (lane >> 4);
                s16x8 v = *(const s16x8*)&Al[row * 64 + ((ch ^ (row & 7)) * 8)];
                af[m] = __builtin_bit_cast(bf16x8, v);
            }
#pragma unroll
            for (int n = 0; n < 4; ++n) {
                int row = wc * 64 + n * 16 + (lane & 15);
                int ch  = ks * 4 + (lane >> 4);
                s16x8 v = *(const s16x8*)&Bl[row * 64 + ((ch ^ (row & 7)) * 8)];
                bfrag[n] = __builtin_bit_cast(bf16x8, v);
            }
#pragma unroll
            for (int m = 0; m < 4; ++m)
#pragma unroll
                for (int n = 0; n < 4; ++n)
                    acc[m][n] = __builtin_amdgcn_mfma_f32_16x16x32_bf16(
                        af[m], bfrag[n], acc[m][n], 0, 0, 0);
        }
        __syncthreads();
    }

    // ---- epilogue: D row=(lane>>4)*4+r, col=lane&15 (m89-verified) ----
    const long crow0 = cbr * batch + (long)mt * 128 + wr * 64;
    const int  col0  = nt * 128 + wc * 64;
    float bv[4];
#pragma unroll
    for (int n = 0; n < 4; ++n)
        bv[n] = bias ? bias[col0 + n * 16 + (lane & 15)] : 0.f;
#pragma unroll
    for (int m = 0; m < 4; ++m) {
#pragma unroll
        for (int r = 0; r < 4; ++r) {
            long row = crow0 + m * 16 + (lane >> 4) * 4 + r;
#pragma unroll
            for (int n = 0; n < 4; ++n) {
                int col = col0 + n * 16 + (lane & 15);
                float v = acc[m][n][r];
                if constexpr (OUTF32)
                    ((float*)Cp)[row * (long)ldc + col] = v + bv[n];
                else
                    ((uint16_t*)Cp)[row * (long)ldc + col] = f2bf(v);
            }
        }
    }
}

// ---------- K3: sim = scale*q^T k (K=4096) + softmax -> attnT[j][i] bf16 ----------
// 1 block per (b,h). 256 thr = 4 waves; wave ds owns d-quarter of each 64-d chunk.
// Thread (ds,tj,ti) accumulates 8x8 block (i=ti*8.., j=tj*8..) in registers.
__global__ __launch_bounds__(256, 1)
void sim_k(const uint16_t* __restrict__ qkv, uint16_t* __restrict__ attnT)
{
    __shared__ float qs[64 * 64];
    __shared__ float ksh[64 * 64];
    __shared__ float red[64 * 64];
    __shared__ float rtmp[64 * 4];
    const int tid = threadIdx.x;
    const int b = blockIdx.x >> 3, h = blockIdx.x & 7;
    const int ds = tid >> 6;
    const int tj = (tid >> 3) & 7;
    const int ti = tid & 7;
    const uint16_t* qb = qkv + (long)b * 4096 * 1536 + h * 64;
    const uint16_t* kb = qb + 512;

    float acc[8][8];
#pragma unroll
    for (int a = 0; a < 8; ++a)
#pragma unroll
        for (int c = 0; c < 8; ++c) acc[a][c] = 0.f;

    for (int c0 = 0; c0 < 4096; c0 += 64) {
        // stage 64 d x 64 (q and k), bf16 -> f32
#pragma unroll
        for (int it = 0; it < 2; ++it) {
            int e = it * 2048 + tid * 8;
            int dd = e >> 6, i = e & 63;
            s16x8 v = *(const s16x8*)(qb + (long)(c0 + dd) * 1536 + i);
#pragma unroll
            for (int u = 0; u < 8; ++u) qs[dd * 64 + i + u] = bf2f((uint16_t)v[u]);
            v = *(const s16x8*)(kb + (long)(c0 + dd) * 1536 + i);
#pragma unroll
            for (int u = 0; u < 8; ++u) ksh[dd * 64 + i + u] = bf2f((uint16_t)v[u]);
        }
        __syncthreads();
        for (int dd = ds * 16; dd < ds * 16 + 16; ++dd) {
            float qa[8], ka[8];
            *(float4*)&qa[0] = *(const float4*)&qs[dd * 64 + ti * 8];
            *(float4*)&qa[4] = *(const float4*)&qs[dd * 64 + ti * 8 + 4];
            *(float4*)&ka[0] = *(const float4*)&ksh[dd * 64 + tj * 8];
            *(float4*)&ka[4] = *(const float4*)&ksh[dd * 64 + tj * 8 + 4];
#pragma unroll
            for (int a = 0; a < 8; ++a)
#pragma unroll
                for (int c = 0; c < 8; ++c)
                    acc[a][c] = fmaf(qa[a], ka[c], acc[a][c]);
        }
        __syncthreads();
    }
    // reduce wave partials into red[i][j]
    for (int w = 0; w < 4; ++w) {
        if (ds == w) {
#pragma unroll
            for (int a = 0; a < 8; ++a)
#pragma unroll
                for (int c = 0; c < 8; ++c) {
                    float* p = &red[(ti * 8 + a) * 64 + tj * 8 + c];
                    *p = (w == 0) ? acc[a][c] : (*p + acc[a][c]);
                }
        }
        __syncthreads();
    }
    // softmax over j: thread -> row i = tid>>2, j-chunk jc = tid&3 (16 cols)
    const int i = tid >> 2, jc = tid & 3;
    float s[16];
#pragma unroll
    for (int j = 0; j < 16; ++j) s[j] = red[i * 64 + jc * 16 + j] * 0.125f;
    float mx = s[0];
#pragma unroll
    for (int j = 1; j < 16; ++j) mx = fmaxf(mx, s[j]);
    rtmp[i * 4 + jc] = mx;
    __syncthreads();
    float m4 = fmaxf(fmaxf(rtmp[i * 4], rtmp[i * 4 + 1]),
                     fmaxf(rtmp[i * 4 + 2], rtmp[i * 4 + 3]));
    float sum = 0.f;
#pragma unroll
    for (int j = 0; j < 16; ++j) { s[j] = __expf(s[j] - m4); sum += s[j]; }
    __syncthreads();
    rtmp[i * 4 + jc] = sum;
    __syncthreads();
    float tot = rtmp[i * 4] + rtmp[i * 4 + 1] + rtmp[i * 4 + 2] + rtmp[i * 4 + 3];
    float inv = 1.f / tot;
    uint16_t* at = attnT + (long)blockIdx.x * 4096;
#pragma unroll
    for (int j = 0; j < 16; ++j)
        at[(jc * 16 + j) * 64 + i] = f2bf(s[j] * inv);
}

// ---------- K4: W2T[b][c][h*64+j] = sum_i attn[i][j]*w_out[h*64+i][c] ----------
// = sum_i w_outT[c][h*64+i] * attnT[j][i]. MFMA with direct-global fragments.
__global__ __launch_bounds__(256, 1)
void w2_k(const uint16_t* __restrict__ attnT, const uint16_t* __restrict__ woutT,
          uint16_t* __restrict__ W2T)
{
    const int tid = threadIdx.x;
    const int lane = tid & 63, wv = tid >> 6;
    const int b = blockIdx.x >> 3, h = blockIdx.x & 7;
    const uint16_t* at = attnT + (long)blockIdx.x * 4096;  // [j][i] 64x64

    bf16x8 bfrag[2][4];
#pragma unroll
    for (int ks = 0; ks < 2; ++ks)
#pragma unroll
        for (int nf = 0; nf < 4; ++nf) {
            s16x8 v = *(const s16x8*)&at[(nf * 16 + (lane & 15)) * 64 + ks * 32 + (lane >> 4) * 8];
            bfrag[ks][nf] = __builtin_bit_cast(bf16x8, v);
        }
    f32x4 acc[8][4];
#pragma unroll
    for (int mf = 0; mf < 8; ++mf)
#pragma unroll
        for (int nf = 0; nf < 4; ++nf) acc[mf][nf] = (f32x4){0.f, 0.f, 0.f, 0.f};
#pragma unroll
    for (int mf = 0; mf < 8; ++mf) {
        int c = wv * 128 + mf * 16 + (lane & 15);
#pragma unroll
        for (int ks = 0; ks < 2; ++ks) {
            s16x8 v = *(const s16x8*)&woutT[(long)c * 512 + h * 64 + ks * 32 + (lane >> 4) * 8];
            bf16x8 af = __builtin_bit_cast(bf16x8, v);
#pragma unroll
            for (int nf = 0; nf < 4; ++nf)
                acc[mf][nf] = __builtin_amdgcn_mfma_f32_16x16x32_bf16(
                    af, bfrag[ks][nf], acc[mf][nf], 0, 0, 0);
        }
    }
    uint16_t* o = W2T + (long)b * 512 * 512;
#pragma unroll
    for (int mf = 0; mf < 8; ++mf)
#pragma unroll
        for (int nf = 0; nf < 4; ++nf)
#pragma unroll
            for (int r = 0; r < 4; ++r) {
                int c = wv * 128 + mf * 16 + (lane >> 4) * 4 + r;
                int j = nf * 16 + (lane & 15);
                o[(long)c * 512 + h * 64 + j] = f2bf(acc[mf][nf][r]);
            }
}

// ---------- launcher ----------
extern "C" void kernel_launch(void* const* d_in, const int* in_sizes, int n_in,
                              void* d_out, int out_size, void* d_ws, size_t ws_size,
                              hipStream_t stream)
{
    const float* x     = (const float*)d_in[0];
    const float* w_qkv = (const float*)d_in[1];
    const float* w_out = (const float*)d_in[2];
    const float* b_out = (const float*)d_in[3];
    float* out = (float*)d_out;

    char* ws = (char*)d_ws;
    uint16_t* qkv   = (uint16_t*)(ws);                   // 131072x1536 bf16 = 402,653,184 B
    uint16_t* wqkvT = (uint16_t*)(ws + 402653184L);      // 1536x512  bf16 = 1,572,864 B
    uint16_t* woutT = (uint16_t*)(ws + 404226048L);      // 512x512   bf16 = 524,288 B
    uint16_t* attnT = (uint16_t*)(ws + 404750336L);      // 256x64x64 bf16 = 2,097,152 B
    uint16_t* W2T   = (uint16_t*)(ws + 406847488L);      // 32x512x512 bf16 = 16,777,216 B
    // total ws use: 423,624,704 B

    tconv_k<<<(512 * 1536) / 256, 256, 0, stream>>>(w_qkv, wqkvT, 512, 1536);
    tconv_k<<<(512 * 512) / 256, 256, 0, stream>>>(w_out, woutT, 512, 512);

    // GEMM1: qkv = x(f32) @ w_qkv  -> bf16 [131072][1536]
    gemm_k<true, false><<<1024 * 12, 256, 0, stream>>>(
        x, wqkvT, qkv, nullptr,
        512 /*K*/, 512 /*lda*/, 1536 /*ldc*/, 1024, 12, 0L, 0L, 0L);

    // sim + softmax -> attnT
    sim_k<<<256, 256, 0, stream>>>(qkv, attnT);

    // per-batch effective projection weights (transposed)
    w2_k<<<256, 256, 0, stream>>>(attnT, woutT, W2T);

    // GEMM2: out[b] = v[b] @ W2T[b]^T + b_out   (v = qkv cols 1024..1535)
    gemm_k<false, true><<<32 * 32 * 4, 256, 0, stream>>>(
        qkv + 1024, W2T, out, b_out,
        512 /*K*/, 1536 /*lda*/, 512 /*ldc*/, 32, 4,
        4096L /*abr*/, 262144L /*bbe*/, 4096L /*cbr*/);
}

// Round 2
// 653.338 us; speedup vs baseline: 1.2211x; 1.2211x over previous
//
#include <hip/hip_runtime.h>
#include <hip/hip_bf16.h>
#include <stdint.h>

// ---------- types ----------
using bf16x8 = __attribute__((ext_vector_type(8))) __bf16;
using s16x8  = __attribute__((ext_vector_type(8))) short;
using f32x4  = __attribute__((ext_vector_type(4))) float;

__device__ __forceinline__ uint16_t f2bf(float f) {
    uint32_t u = __builtin_bit_cast(uint32_t, f);
    u += 0x7fffu + ((u >> 16) & 1u);   // RNE
    return (uint16_t)(u >> 16);
}
__device__ __forceinline__ float bf2f(uint16_t h) {
    return __builtin_bit_cast(float, (uint32_t)h << 16);
}

// async global->LDS, 16B per lane. LDS dest must be wave-uniform base (+lane*16 by HW).
__device__ __forceinline__ void async16(uint16_t* lds_dst, const uint16_t* g_src) {
    __builtin_amdgcn_global_load_lds(
        (const __attribute__((address_space(1))) void*)g_src,
        (__attribute__((address_space(3))) void*)lds_dst,
        16, 0, 0);
}

// ---------- K0: transpose + f32->bf16 convert (for weights) ----------
__global__ void tconv_k(const float* __restrict__ in, uint16_t* __restrict__ out,
                        int R, int C) {
    int idx = blockIdx.x * 256 + threadIdx.x;
    if (idx >= R * C) return;
    int r = idx / C, c = idx - r * C;
    out[(long)c * R + r] = f2bf(in[idx]);
}

// ---------- GEMM: C[M x N] = A[M x K] * Bt[N x K]^T, 128x128 tile, BK=64 ----------
// XCD-aware bijective swizzle (T1): grids here are always %8==0; each XCD gets a
// contiguous logical-tile chunk so A-panel-sharing blocks (consecutive nt) hit one L2.
template<bool AF32, bool OUTF32>
__global__ __launch_bounds__(256, 2)
void gemm_k(const void* __restrict__ Ap, const uint16_t* __restrict__ Bt,
            void* __restrict__ Cp, const float* __restrict__ bias,
            int K, int lda, int ldc, int mtiles, int ntiles,
            long abr, long bbe, long cbr)
{
    __shared__ uint16_t Al[128 * 64];
    __shared__ uint16_t Bl[128 * 64];
    const int tid  = threadIdx.x;
    const int lane = tid & 63;
    const int wv   = tid >> 6;
    const int wr   = wv >> 1, wc = wv & 1;

    // XCD swizzle: hw block b runs on XCD b%8; give XCD x logical ids [x*q8, (x+1)*q8)
    const int nwg = gridDim.x;
    const int q8  = nwg >> 3;
    const int l   = (blockIdx.x & 7) * q8 + (blockIdx.x >> 3);

    const int per   = mtiles * ntiles;
    const int batch = l / per;
    const int rem   = l - batch * per;
    const int mt    = rem / ntiles, nt = rem - mt * ntiles;

    const long arow0 = abr * batch + (long)mt * 128;
    const uint16_t* btb = Bt + bbe * batch + (long)nt * 128 * K;

    f32x4 acc[4][4];
#pragma unroll
    for (int m = 0; m < 4; ++m)
#pragma unroll
        for (int n = 0; n < 4; ++n) acc[m][n] = (f32x4){0.f, 0.f, 0.f, 0.f};

    for (int k0 = 0; k0 < K; k0 += 64) {
        // ---- stage B (bf16, async direct-to-LDS, pre-swizzled source) ----
#pragma unroll
        for (int i = 0; i < 4; ++i) {
            int cb  = i * 256 + wv * 64;
            int ci  = cb + lane;
            int row = ci >> 3;
            int cs  = (ci & 7) ^ (row & 7);
            async16(&Bl[cb * 8], btb + (long)row * K + (k0 + cs * 8));
        }
        // ---- stage A ----
        if constexpr (AF32) {
            const float* Af = (const float*)Ap;
#pragma unroll
            for (int j = 0; j < 4; ++j) {
                int ci  = j * 256 + tid;
                int row = ci >> 3;
                int sl  = ci & 7;
                const float* g = Af + (arow0 + row) * (long)lda + (k0 + sl * 8);
                float4 v0 = *(const float4*)g;
                float4 v1 = *(const float4*)(g + 4);
                uint16_t t[8];
                t[0] = f2bf(v0.x); t[1] = f2bf(v0.y); t[2] = f2bf(v0.z); t[3] = f2bf(v0.w);
                t[4] = f2bf(v1.x); t[5] = f2bf(v1.y); t[6] = f2bf(v1.z); t[7] = f2bf(v1.w);
                *(s16x8*)&Al[row * 64 + ((sl ^ (row & 7)) * 8)] = *(const s16x8*)t;
            }
        } else {
            const uint16_t* Ab = (const uint16_t*)Ap;
#pragma unroll
            for (int i = 0; i < 4; ++i) {
                int cb  = i * 256 + wv * 64;
                int ci  = cb + lane;
                int row = ci >> 3;
                int cs  = (ci & 7) ^ (row & 7);
                async16(&Al[cb * 8], Ab + (arow0 + row) * (long)lda + (k0 + cs * 8));
            }
        }
        __syncthreads();

        // ---- compute: 2 k-subs x 4x4 fragments ----
#pragma unroll
        for (int ks = 0; ks < 2; ++ks) {
            bf16x8 af[4], bfrag[4];
#pragma unroll
            for (int m = 0; m < 4; ++m) {
                int row = wr * 64 + m * 16 + (lane & 15);
                int ch  = ks * 4 + (lane >> 4);
                s16x8 v = *(const s16x8*)&Al[row * 64 + ((ch ^ (row & 7)) * 8)];
                af[m] = __builtin_bit_cast(bf16x8, v);
            }
#pragma unroll
            for (int n = 0; n < 4; ++n) {
                int row = wc * 64 + n * 16 + (lane & 15);
                int ch  = ks * 4 + (lane >> 4);
                s16x8 v = *(const s16x8*)&Bl[row * 64 + ((ch ^ (row & 7)) * 8)];
                bfrag[n] = __builtin_bit_cast(bf16x8, v);
            }
#pragma unroll
            for (int m = 0; m < 4; ++m)
#pragma unroll
                for (int n = 0; n < 4; ++n)
                    acc[m][n] = __builtin_amdgcn_mfma_f32_16x16x32_bf16(
                        af[m], bfrag[n], acc[m][n], 0, 0, 0);
        }
        __syncthreads();
    }

    // ---- epilogue ----
    const long crow0 = cbr * batch + (long)mt * 128 + wr * 64;
    const int  col0  = nt * 128 + wc * 64;
    float bv[4];
#pragma unroll
    for (int n = 0; n < 4; ++n)
        bv[n] = bias ? bias[col0 + n * 16 + (lane & 15)] : 0.f;
#pragma unroll
    for (int m = 0; m < 4; ++m) {
#pragma unroll
        for (int r = 0; r < 4; ++r) {
            long row = crow0 + m * 16 + (lane >> 4) * 4 + r;
#pragma unroll
            for (int n = 0; n < 4; ++n) {
                int col = col0 + n * 16 + (lane & 15);
                float v = acc[m][n][r];
                if constexpr (OUTF32)
                    ((float*)Cp)[row * (long)ldc + col] = v + bv[n];
                else
                    ((uint16_t*)Cp)[row * (long)ldc + col] = f2bf(v);
            }
        }
    }
}

// ---------- K3a: partial sim over a 1024-wide d segment ----------
// grid = 256 bh * 4 seg. Block (bh,seg): simP[bh*4+seg][i][j] = sum_{d in seg} q^T q...
__global__ __launch_bounds__(256, 2)
void sim_part_k(const uint16_t* __restrict__ qkv, float* __restrict__ simP)
{
    __shared__ float qs[64 * 64];
    __shared__ float ksh[64 * 64];
    __shared__ float red[64 * 64];
    const int tid = threadIdx.x;
    const int bh = blockIdx.x >> 2, seg = blockIdx.x & 3;
    const int b = bh >> 3, h = bh & 7;
    const int ds = tid >> 6;
    const int tj = (tid >> 3) & 7;
    const int ti = tid & 7;
    const uint16_t* qb = qkv + (long)b * 4096 * 1536 + h * 64;
    const uint16_t* kb = qb + 512;

    float acc[8][8];
#pragma unroll
    for (int a = 0; a < 8; ++a)
#pragma unroll
        for (int c = 0; c < 8; ++c) acc[a][c] = 0.f;

    for (int c0 = seg * 1024; c0 < seg * 1024 + 1024; c0 += 64) {
#pragma unroll
        for (int it = 0; it < 2; ++it) {
            int e = it * 2048 + tid * 8;
            int dd = e >> 6, i = e & 63;
            s16x8 v = *(const s16x8*)(qb + (long)(c0 + dd) * 1536 + i);
#pragma unroll
            for (int u = 0; u < 8; ++u) qs[dd * 64 + i + u] = bf2f((uint16_t)v[u]);
            v = *(const s16x8*)(kb + (long)(c0 + dd) * 1536 + i);
#pragma unroll
            for (int u = 0; u < 8; ++u) ksh[dd * 64 + i + u] = bf2f((uint16_t)v[u]);
        }
        __syncthreads();
        for (int dd = ds * 16; dd < ds * 16 + 16; ++dd) {
            float qa[8], ka[8];
            *(float4*)&qa[0] = *(const float4*)&qs[dd * 64 + ti * 8];
            *(float4*)&qa[4] = *(const float4*)&qs[dd * 64 + ti * 8 + 4];
            *(float4*)&ka[0] = *(const float4*)&ksh[dd * 64 + tj * 8];
            *(float4*)&ka[4] = *(const float4*)&ksh[dd * 64 + tj * 8 + 4];
#pragma unroll
            for (int a = 0; a < 8; ++a)
#pragma unroll
                for (int c = 0; c < 8; ++c)
                    acc[a][c] = fmaf(qa[a], ka[c], acc[a][c]);
        }
        __syncthreads();
    }
    // reduce wave partials into red[i][j]
    for (int w = 0; w < 4; ++w) {
        if (ds == w) {
#pragma unroll
            for (int a = 0; a < 8; ++a)
#pragma unroll
                for (int c = 0; c < 8; ++c) {
                    float* p = &red[(ti * 8 + a) * 64 + tj * 8 + c];
                    *p = (w == 0) ? acc[a][c] : (*p + acc[a][c]);
                }
        }
        __syncthreads();
    }
    float* o = simP + (long)blockIdx.x * 4096;
#pragma unroll
    for (int u = 0; u < 4; ++u)
        ((float4*)o)[tid * 4 + u] = ((const float4*)red)[tid * 4 + u];
}

// ---------- K3b: sum 4 partials + softmax -> attnT[j][i] bf16 ----------
__global__ __launch_bounds__(256, 4)
void softmax_k(const float* __restrict__ simP, uint16_t* __restrict__ attnT)
{
    __shared__ float rtmp[64 * 4];
    const int tid = threadIdx.x;
    const int i = tid >> 2, jc = tid & 3;
    const float* base = simP + (long)blockIdx.x * 4 * 4096;
    float s[16];
#pragma unroll
    for (int j = 0; j < 16; ++j) {
        float acc = 0.f;
#pragma unroll
        for (int seg = 0; seg < 4; ++seg)
            acc += base[seg * 4096 + i * 64 + jc * 16 + j];
        s[j] = acc * 0.125f;
    }
    float mx = s[0];
#pragma unroll
    for (int j = 1; j < 16; ++j) mx = fmaxf(mx, s[j]);
    rtmp[i * 4 + jc] = mx;
    __syncthreads();
    float m4 = fmaxf(fmaxf(rtmp[i * 4], rtmp[i * 4 + 1]),
                     fmaxf(rtmp[i * 4 + 2], rtmp[i * 4 + 3]));
    float sum = 0.f;
#pragma unroll
    for (int j = 0; j < 16; ++j) { s[j] = __expf(s[j] - m4); sum += s[j]; }
    __syncthreads();
    rtmp[i * 4 + jc] = sum;
    __syncthreads();
    float tot = rtmp[i * 4] + rtmp[i * 4 + 1] + rtmp[i * 4 + 2] + rtmp[i * 4 + 3];
    float inv = 1.f / tot;
    uint16_t* at = attnT + (long)blockIdx.x * 4096;
#pragma unroll
    for (int j = 0; j < 16; ++j)
        at[(jc * 16 + j) * 64 + i] = f2bf(s[j] * inv);
}

// ---------- K4: W2T[b][c][h*64+j] = sum_i attn[i][j]*w_out[h*64+i][c] ----------
__global__ __launch_bounds__(256, 1)
void w2_k(const uint16_t* __restrict__ attnT, const uint16_t* __restrict__ woutT,
          uint16_t* __restrict__ W2T)
{
    const int tid = threadIdx.x;
    const int lane = tid & 63, wv = tid >> 6;
    const int b = blockIdx.x >> 3, h = blockIdx.x & 7;
    const uint16_t* at = attnT + (long)blockIdx.x * 4096;

    bf16x8 bfrag[2][4];
#pragma unroll
    for (int ks = 0; ks < 2; ++ks)
#pragma unroll
        for (int nf = 0; nf < 4; ++nf) {
            s16x8 v = *(const s16x8*)&at[(nf * 16 + (lane & 15)) * 64 + ks * 32 + (lane >> 4) * 8];
            bfrag[ks][nf] = __builtin_bit_cast(bf16x8, v);
        }
    f32x4 acc[8][4];
#pragma unroll
    for (int mf = 0; mf < 8; ++mf)
#pragma unroll
        for (int nf = 0; nf < 4; ++nf) acc[mf][nf] = (f32x4){0.f, 0.f, 0.f, 0.f};
#pragma unroll
    for (int mf = 0; mf < 8; ++mf) {
        int c = wv * 128 + mf * 16 + (lane & 15);
#pragma unroll
        for (int ks = 0; ks < 2; ++ks) {
            s16x8 v = *(const s16x8*)&woutT[(long)c * 512 + h * 64 + ks * 32 + (lane >> 4) * 8];
            bf16x8 af = __builtin_bit_cast(bf16x8, v);
#pragma unroll
            for (int nf = 0; nf < 4; ++nf)
                acc[mf][nf] = __builtin_amdgcn_mfma_f32_16x16x32_bf16(
                    af, bfrag[ks][nf], acc[mf][nf], 0, 0, 0);
        }
    }
    uint16_t* o = W2T + (long)b * 512 * 512;
#pragma unroll
    for (int mf = 0; mf < 8; ++mf)
#pragma unroll
        for (int nf = 0; nf < 4; ++nf)
#pragma unroll
            for (int r = 0; r < 4; ++r) {
                int c = wv * 128 + mf * 16 + (lane >> 4) * 4 + r;
                int j = nf * 16 + (lane & 15);
                o[(long)c * 512 + h * 64 + j] = f2bf(acc[mf][nf][r]);
            }
}

// ---------- launcher ----------
extern "C" void kernel_launch(void* const* d_in, const int* in_sizes, int n_in,
                              void* d_out, int out_size, void* d_ws, size_t ws_size,
                              hipStream_t stream)
{
    const float* x     = (const float*)d_in[0];
    const float* w_qkv = (const float*)d_in[1];
    const float* w_out = (const float*)d_in[2];
    const float* b_out = (const float*)d_in[3];
    float* out = (float*)d_out;

    char* ws = (char*)d_ws;
    uint16_t* qkv   = (uint16_t*)(ws);                   // 402,653,184 B
    uint16_t* wqkvT = (uint16_t*)(ws + 402653184L);      // 1,572,864 B
    uint16_t* woutT = (uint16_t*)(ws + 404226048L);      // 524,288 B
    uint16_t* attnT = (uint16_t*)(ws + 404750336L);      // 2,097,152 B
    // simP (16,777,216 B f32) aliases W2T: simP dead after softmax_k,
    // W2T written only afterwards (w2_k). Both rewritten every call.
    float*    simP  = (float*)(ws + 406847488L);
    uint16_t* W2T   = (uint16_t*)(ws + 406847488L);      // 16,777,216 B
    // total ws use: 423,624,704 B

    tconv_k<<<(512 * 1536) / 256, 256, 0, stream>>>(w_qkv, wqkvT, 512, 1536);
    tconv_k<<<(512 * 512) / 256, 256, 0, stream>>>(w_out, woutT, 512, 512);

    // GEMM1: qkv = x(f32) @ w_qkv  -> bf16 [131072][1536]
    gemm_k<true, false><<<1024 * 12, 256, 0, stream>>>(
        x, wqkvT, qkv, nullptr,
        512, 512, 1536, 1024, 12, 0L, 0L, 0L);

    // sim partials (4-way split-K over d) + softmax
    sim_part_k<<<1024, 256, 0, stream>>>(qkv, simP);
    softmax_k<<<256, 256, 0, stream>>>(simP, attnT);

    // per-batch effective projection weights (transposed)
    w2_k<<<256, 256, 0, stream>>>(attnT, woutT, W2T);

    // GEMM2: out[b] = v[b] @ W2T[b]^T + b_out
    gemm_k<false, true><<<32 * 32 * 4, 256, 0, stream>>>(
        qkv + 1024, W2T, out, b_out,
        512, 1536, 512, 32, 4,
        4096L, 262144L, 4096L);
}

// Round 3
// 629.057 us; speedup vs baseline: 1.2682x; 1.0386x over previous
//
#include <hip/hip_runtime.h>
#include <hip/hip_bf16.h>
#include <stdint.h>

// ---------- types ----------
using bf16x8 = __attribute__((ext_vector_type(8))) __bf16;
using s16x8  = __attribute__((ext_vector_type(8))) short;
using f32x4  = __attribute__((ext_vector_type(4))) float;

__device__ __forceinline__ uint16_t f2bf(float f) {
    uint32_t u = __builtin_bit_cast(uint32_t, f);
    u += 0x7fffu + ((u >> 16) & 1u);   // RNE
    return (uint16_t)(u >> 16);
}
__device__ __forceinline__ float bf2f(uint16_t h) {
    return __builtin_bit_cast(float, (uint32_t)h << 16);
}

// async global->LDS, 16B per lane. LDS dest wave-uniform base (+lane*16 by HW);
// global source per-lane.
__device__ __forceinline__ void async16(uint16_t* lds_dst, const uint16_t* g_src) {
    __builtin_amdgcn_global_load_lds(
        (const __attribute__((address_space(1))) void*)g_src,
        (__attribute__((address_space(3))) void*)lds_dst,
        16, 0, 0);
}

// ---------- K0: transpose + f32->bf16 convert (weights) ----------
__global__ void tconv_k(const float* __restrict__ in, uint16_t* __restrict__ out,
                        int R, int C) {
    int idx = blockIdx.x * 256 + threadIdx.x;
    if (idx >= R * C) return;
    int r = idx / C, c = idx - r * C;
    out[(long)c * R + r] = f2bf(in[idx]);
}

// ---------- K0b: x f32 -> bf16 (row-layout preserved) ----------
__global__ void xconv_k(const float* __restrict__ in, uint16_t* __restrict__ out) {
    long base = ((long)blockIdx.x * 256 + threadIdx.x) * 8;
    float4 v0 = *(const float4*)(in + base);
    float4 v1 = *(const float4*)(in + base + 4);
    uint16_t t[8];
    t[0] = f2bf(v0.x); t[1] = f2bf(v0.y); t[2] = f2bf(v0.z); t[3] = f2bf(v0.w);
    t[4] = f2bf(v1.x); t[5] = f2bf(v1.y); t[6] = f2bf(v1.z); t[7] = f2bf(v1.w);
    *(s16x8*)(out + base) = *(const s16x8*)t;
}

// ---------- g3: 256x256 tile, BK=32, 3-buffer counted-vmcnt pipeline ----------
// C[M x N] = A[M x K] * Bt[N x K]^T. A,Bt bf16. 512 thr = 8 waves (2M x 4N).
// LDS slot layout per operand: slot s (16B) holds global (row=s>>2, chunk=(s&3)^((row>>1)&3)).
// ds_read_b128 frags land exactly 2-way per bank (free); gload_lds sources stay
// row-coalesced (swizzle applied to SOURCE, LDS linear — rule #21).
template<bool OUTF32>
__global__ __launch_bounds__(512, 1)
void g3_k(const uint16_t* __restrict__ A, const uint16_t* __restrict__ Bt,
          void* __restrict__ Cp, const float* __restrict__ bias,
          int K, int lda, int ldb, int ldc, int mtiles, int ntiles,
          long abr, long bbe, long cbr)
{
    __shared__ uint16_t lds[49152];   // 3 bufs x (A 8192 + B 8192) elems = 96 KiB
    const int tid  = threadIdx.x;
    const int lane = tid & 63;
    const int wv   = tid >> 6;
    const int wr   = wv >> 2, wc = wv & 3;

    // XCD-aware bijective swizzle (grid % 8 == 0 always here)
    const int q8 = gridDim.x >> 3;
    const int l  = (blockIdx.x & 7) * q8 + (blockIdx.x >> 3);
    const int per   = mtiles * ntiles;
    const int batch = l / per;
    const int rem   = l - batch * per;
    const int mt    = rem / ntiles, nt = rem - mt * ntiles;

    const long arow0 = abr * batch + (long)mt * 256;
    const uint16_t* btb = Bt + bbe * batch + (long)nt * 256 * ldb;

    // staging per-lane geometry
    const int srs = lane >> 2;     // sub-row within 16-row group
    const int scp = lane & 3;      // stored chunk slot c'
    // fragment per-lane geometry (identical for A and B)
    const int fr = lane & 15;
    const int fc = (lane >> 4) ^ ((fr >> 1) & 3);
    const int aoff = (wr * 128 + fr) * 32 + fc * 8;
    const int boff = (wc * 64  + fr) * 32 + fc * 8;

    const int NT = K >> 5;

    auto stageA = [&](int bsel, int k0) {
#pragma unroll
        for (int i = 0; i < 2; ++i) {
            int r = i * 128 + wv * 16 + srs;
            int c = scp ^ ((r >> 1) & 3);
            async16(&lds[bsel * 16384 + i * 4096 + wv * 512],
                    A + (arow0 + r) * (long)lda + (k0 + c * 8));
        }
    };
    auto stageB = [&](int bsel, int k0) {
#pragma unroll
        for (int i = 0; i < 2; ++i) {
            int r = i * 128 + wv * 16 + srs;
            int c = scp ^ ((r >> 1) & 3);
            async16(&lds[bsel * 16384 + 8192 + i * 4096 + wv * 512],
                    btb + (long)r * ldb + (k0 + c * 8));
        }
    };

    f32x4 acc[8][4];
#pragma unroll
    for (int m = 0; m < 8; ++m)
#pragma unroll
        for (int n = 0; n < 4; ++n) acc[m][n] = (f32x4){0.f, 0.f, 0.f, 0.f};

    // prologue: tiles 0,1 in flight; drain tile 0, publish.
    stageA(0, 0);  stageB(0, 0);
    stageA(1, 32); stageB(1, 32);
    asm volatile("s_waitcnt vmcnt(4)" ::: "memory");
    __builtin_amdgcn_s_barrier();

    int cur = 0, stg = 2;
    for (int t = 0; t < NT; ++t) {
        const uint16_t* Ab = &lds[cur * 16384];
        const uint16_t* Bb = Ab + 8192;
        const bool pf = (t + 2) < NT;
        const int kpf = (t + 2) << 5;
        bf16x8 bfr[4], afr[4];
        // ---- phase 0: B-all + A m0-3 ----
#pragma unroll
        for (int n = 0; n < 4; ++n)
            bfr[n] = __builtin_bit_cast(bf16x8, *(const s16x8*)&Bb[boff + n * 512]);
#pragma unroll
        for (int m = 0; m < 4; ++m)
            afr[m] = __builtin_bit_cast(bf16x8, *(const s16x8*)&Ab[aoff + m * 512]);
        if (pf) stageA(stg, kpf);
        __builtin_amdgcn_s_barrier();
        __builtin_amdgcn_s_setprio(1);
#pragma unroll
        for (int m = 0; m < 4; ++m)
#pragma unroll
            for (int n = 0; n < 4; ++n)
                acc[m][n] = __builtin_amdgcn_mfma_f32_16x16x32_bf16(
                    afr[m], bfr[n], acc[m][n], 0, 0, 0);
        __builtin_amdgcn_s_setprio(0);
        __builtin_amdgcn_s_barrier();
        // ---- phase 1: A m4-7 (B held in regs) ----
#pragma unroll
        for (int m = 0; m < 4; ++m)
            afr[m] = __builtin_bit_cast(bf16x8, *(const s16x8*)&Ab[aoff + (m + 4) * 512]);
        if (pf) stageB(stg, kpf);
        __builtin_amdgcn_s_barrier();
        __builtin_amdgcn_s_setprio(1);
#pragma unroll
        for (int m = 0; m < 4; ++m)
#pragma unroll
            for (int n = 0; n < 4; ++n)
                acc[m + 4][n] = __builtin_amdgcn_mfma_f32_16x16x32_bf16(
                    afr[m], bfr[n], acc[m + 4][n], 0, 0, 0);
        __builtin_amdgcn_s_setprio(0);
        // boundary: own t+1 contributions landed BEFORE publishing barrier
        if (pf) { asm volatile("s_waitcnt vmcnt(4)" ::: "memory"); }
        else    { asm volatile("s_waitcnt vmcnt(0)" ::: "memory"); }
        __builtin_amdgcn_s_barrier();
        cur = (cur == 2) ? 0 : cur + 1;
        stg = (stg == 2) ? 0 : stg + 1;
    }

    // ---- epilogue: D row=(lane>>4)*4+r, col=lane&15 (m89-verified) ----
    const long crow0 = cbr * batch + (long)mt * 256 + wr * 128;
    const int  col0  = nt * 256 + wc * 64;
    float bv[4];
#pragma unroll
    for (int n = 0; n < 4; ++n)
        bv[n] = bias ? bias[col0 + n * 16 + (lane & 15)] : 0.f;
#pragma unroll
    for (int m = 0; m < 8; ++m) {
#pragma unroll
        for (int r = 0; r < 4; ++r) {
            long row = crow0 + m * 16 + (lane >> 4) * 4 + r;
#pragma unroll
            for (int n = 0; n < 4; ++n) {
                int col = col0 + n * 16 + (lane & 15);
                float v = acc[m][n][r];
                if constexpr (OUTF32)
                    ((float*)Cp)[row * (long)ldc + col] = v + bv[n];
                else
                    ((uint16_t*)Cp)[row * (long)ldc + col] = f2bf(v);
            }
        }
    }
}

// ---------- K3a: partial sim over a 1024-wide d segment ----------
__global__ __launch_bounds__(256, 2)
void sim_part_k(const uint16_t* __restrict__ qkv, float* __restrict__ simP)
{
    __shared__ float qs[64 * 64];
    __shared__ float ksh[64 * 64];
    __shared__ float red[64 * 64];
    const int tid = threadIdx.x;
    const int bh = blockIdx.x >> 2, seg = blockIdx.x & 3;
    const int b = bh >> 3, h = bh & 7;
    const int ds = tid >> 6;
    const int tj = (tid >> 3) & 7;
    const int ti = tid & 7;
    const uint16_t* qb = qkv + (long)b * 4096 * 1536 + h * 64;
    const uint16_t* kb = qb + 512;

    float acc[8][8];
#pragma unroll
    for (int a = 0; a < 8; ++a)
#pragma unroll
        for (int c = 0; c < 8; ++c) acc[a][c] = 0.f;

    for (int c0 = seg * 1024; c0 < seg * 1024 + 1024; c0 += 64) {
#pragma unroll
        for (int it = 0; it < 2; ++it) {
            int e = it * 2048 + tid * 8;
            int dd = e >> 6, i = e & 63;
            s16x8 v = *(const s16x8*)(qb + (long)(c0 + dd) * 1536 + i);
#pragma unroll
            for (int u = 0; u < 8; ++u) qs[dd * 64 + i + u] = bf2f((uint16_t)v[u]);
            v = *(const s16x8*)(kb + (long)(c0 + dd) * 1536 + i);
#pragma unroll
            for (int u = 0; u < 8; ++u) ksh[dd * 64 + i + u] = bf2f((uint16_t)v[u]);
        }
        __syncthreads();
        for (int dd = ds * 16; dd < ds * 16 + 16; ++dd) {
            float qa[8], ka[8];
            *(float4*)&qa[0] = *(const float4*)&qs[dd * 64 + ti * 8];
            *(float4*)&qa[4] = *(const float4*)&qs[dd * 64 + ti * 8 + 4];
            *(float4*)&ka[0] = *(const float4*)&ksh[dd * 64 + tj * 8];
            *(float4*)&ka[4] = *(const float4*)&ksh[dd * 64 + tj * 8 + 4];
#pragma unroll
            for (int a = 0; a < 8; ++a)
#pragma unroll
                for (int c = 0; c < 8; ++c)
                    acc[a][c] = fmaf(qa[a], ka[c], acc[a][c]);
        }
        __syncthreads();
    }
    for (int w = 0; w < 4; ++w) {
        if (ds == w) {
#pragma unroll
            for (int a = 0; a < 8; ++a)
#pragma unroll
                for (int c = 0; c < 8; ++c) {
                    float* p = &red[(ti * 8 + a) * 64 + tj * 8 + c];
                    *p = (w == 0) ? acc[a][c] : (*p + acc[a][c]);
                }
        }
        __syncthreads();
    }
    float* o = simP + (long)blockIdx.x * 4096;
#pragma unroll
    for (int u = 0; u < 4; ++u)
        ((float4*)o)[tid * 4 + u] = ((const float4*)red)[tid * 4 + u];
}

// ---------- K3b: sum 4 partials + softmax -> attnT[j][i] bf16 ----------
__global__ __launch_bounds__(256, 4)
void softmax_k(const float* __restrict__ simP, uint16_t* __restrict__ attnT)
{
    __shared__ float rtmp[64 * 4];
    const int tid = threadIdx.x;
    const int i = tid >> 2, jc = tid & 3;
    const float* base = simP + (long)blockIdx.x * 4 * 4096;
    float s[16];
#pragma unroll
    for (int j = 0; j < 16; ++j) {
        float acc = 0.f;
#pragma unroll
        for (int seg = 0; seg < 4; ++seg)
            acc += base[seg * 4096 + i * 64 + jc * 16 + j];
        s[j] = acc * 0.125f;
    }
    float mx = s[0];
#pragma unroll
    for (int j = 1; j < 16; ++j) mx = fmaxf(mx, s[j]);
    rtmp[i * 4 + jc] = mx;
    __syncthreads();
    float m4 = fmaxf(fmaxf(rtmp[i * 4], rtmp[i * 4 + 1]),
                     fmaxf(rtmp[i * 4 + 2], rtmp[i * 4 + 3]));
    float sum = 0.f;
#pragma unroll
    for (int j = 0; j < 16; ++j) { s[j] = __expf(s[j] - m4); sum += s[j]; }
    __syncthreads();
    rtmp[i * 4 + jc] = sum;
    __syncthreads();
    float tot = rtmp[i * 4] + rtmp[i * 4 + 1] + rtmp[i * 4 + 2] + rtmp[i * 4 + 3];
    float inv = 1.f / tot;
    uint16_t* at = attnT + (long)blockIdx.x * 4096;
#pragma unroll
    for (int j = 0; j < 16; ++j)
        at[(jc * 16 + j) * 64 + i] = f2bf(s[j] * inv);
}

// ---------- K4: W2T[b][c][h*64+j] = sum_i attn[i][j]*w_out[h*64+i][c] ----------
__global__ __launch_bounds__(256, 1)
void w2_k(const uint16_t* __restrict__ attnT, const uint16_t* __restrict__ woutT,
          uint16_t* __restrict__ W2T)
{
    const int tid = threadIdx.x;
    const int lane = tid & 63, wv = tid >> 6;
    const int b = blockIdx.x >> 3, h = blockIdx.x & 7;
    const uint16_t* at = attnT + (long)blockIdx.x * 4096;

    bf16x8 bfrag[2][4];
#pragma unroll
    for (int ks = 0; ks < 2; ++ks)
#pragma unroll
        for (int nf = 0; nf < 4; ++nf) {
            s16x8 v = *(const s16x8*)&at[(nf * 16 + (lane & 15)) * 64 + ks * 32 + (lane >> 4) * 8];
            bfrag[ks][nf] = __builtin_bit_cast(bf16x8, v);
        }
    f32x4 acc[8][4];
#pragma unroll
    for (int mf = 0; mf < 8; ++mf)
#pragma unroll
        for (int nf = 0; nf < 4; ++nf) acc[mf][nf] = (f32x4){0.f, 0.f, 0.f, 0.f};
#pragma unroll
    for (int mf = 0; mf < 8; ++mf) {
        int c = wv * 128 + mf * 16 + (lane & 15);
#pragma unroll
        for (int ks = 0; ks < 2; ++ks) {
            s16x8 v = *(const s16x8*)&woutT[(long)c * 512 + h * 64 + ks * 32 + (lane >> 4) * 8];
            bf16x8 af = __builtin_bit_cast(bf16x8, v);
#pragma unroll
            for (int nf = 0; nf < 4; ++nf)
                acc[mf][nf] = __builtin_amdgcn_mfma_f32_16x16x32_bf16(
                    af, bfrag[ks][nf], acc[mf][nf], 0, 0, 0);
        }
    }
    uint16_t* o = W2T + (long)b * 512 * 512;
#pragma unroll
    for (int mf = 0; mf < 8; ++mf)
#pragma unroll
        for (int nf = 0; nf < 4; ++nf)
#pragma unroll
            for (int r = 0; r < 4; ++r) {
                int c = wv * 128 + mf * 16 + (lane >> 4) * 4 + r;
                int j = nf * 16 + (lane & 15);
                o[(long)c * 512 + h * 64 + j] = f2bf(acc[mf][nf][r]);
            }
}

// ---------- launcher ----------
extern "C" void kernel_launch(void* const* d_in, const int* in_sizes, int n_in,
                              void* d_out, int out_size, void* d_ws, size_t ws_size,
                              hipStream_t stream)
{
    const float* x     = (const float*)d_in[0];
    const float* w_qkv = (const float*)d_in[1];
    const float* w_out = (const float*)d_in[2];
    const float* b_out = (const float*)d_in[3];
    float* out = (float*)d_out;

    char* ws = (char*)d_ws;
    uint16_t* qkv   = (uint16_t*)(ws);                   // 402,653,184 B
    uint16_t* wqkvT = (uint16_t*)(ws + 402653184L);      // 1,572,864 B
    uint16_t* woutT = (uint16_t*)(ws + 404226048L);      // 524,288 B
    uint16_t* attnT = (uint16_t*)(ws + 404750336L);      // 2,097,152 B
    float*    simP  = (float*)(ws + 406847488L);         // aliases W2T (simP dead first)
    uint16_t* W2T   = (uint16_t*)(ws + 406847488L);      // 16,777,216 B

    // xb (bf16 x, 134,217,728 B) lives in d_out: dead before GEMM2 overwrites d_out.
    uint16_t* xb = (uint16_t*)d_out;

    tconv_k<<<(512 * 1536) / 256, 256, 0, stream>>>(w_qkv, wqkvT, 512, 1536);
    tconv_k<<<(512 * 512) / 256, 256, 0, stream>>>(w_out, woutT, 512, 512);
    xconv_k<<<32768, 256, 0, stream>>>(x, xb);

    // GEMM1: qkv = xb @ wqkvT^T -> bf16 [131072][1536]
    g3_k<false><<<3072, 512, 0, stream>>>(
        xb, wqkvT, qkv, nullptr,
        512 /*K*/, 512 /*lda*/, 512 /*ldb*/, 1536 /*ldc*/, 512, 6, 0L, 0L, 0L);

    // sim partials (4-way split-K over d) + softmax
    sim_part_k<<<1024, 256, 0, stream>>>(qkv, simP);
    softmax_k<<<256, 256, 0, stream>>>(simP, attnT);

    // per-batch effective projection weights (transposed)
    w2_k<<<256, 256, 0, stream>>>(attnT, woutT, W2T);

    // GEMM2: out[b] = v[b] @ W2T[b]^T + b_out
    g3_k<true><<<1024, 512, 0, stream>>>(
        qkv + 1024, W2T, out, b_out,
        512 /*K*/, 1536 /*lda*/, 512 /*ldb*/, 512 /*ldc*/, 16, 2,
        4096L, 262144L, 4096L);
}